// Round 8
// baseline (203.290 us; speedup 1.0000x reference)
//
#include <hip/hip_runtime.h>
#include <hip/hip_bf16.h>
#include <string.h>

#define NB   2
#define SEQ  2048
#define EMB  1024
#define NH   16
#define HD   64
// softmax uses exp2: fold SCALE*log2(e) into Q pre-scale
#define QSCALE 0.045084219f       // (1/32) * log2(e)

typedef __attribute__((ext_vector_type(8))) short short8;   // 8 x bf16
typedef __attribute__((ext_vector_type(4))) float f32x4;    // MFMA C/D

#define MFMA(a, b, c) __builtin_amdgcn_mfma_f32_16x16x32_bf16(a, b, c, 0, 0, 0)
#define EXP2(x) __builtin_amdgcn_exp2f(x)

__device__ __forceinline__ unsigned short f2bf(float x) {
    union { float f; unsigned u; } v; v.f = x;
    unsigned r = v.u + 0x7fffu + ((v.u >> 16) & 1u);   // RNE
    return (unsigned short)(r >> 16);
}
__device__ __forceinline__ unsigned packbf2(float a, float b) {
    __hip_bfloat162 h = __float22bfloat162_rn(make_float2(a, b));  // hw v_cvt_pk
    unsigned u; memcpy(&u, &h, 4);
    return u;
}
// async global->LDS, 16B per lane; LDS dest = uniform base + lane*16 (linear)
__device__ __forceinline__ void gload16(const void* g, void* l) {
    __builtin_amdgcn_global_load_lds(
        (const __attribute__((address_space(1))) void*)g,
        (__attribute__((address_space(3))) void*)l, 16, 0, 0);
}

// ---------------------------------------------------------------------------
// Kernel 0: convert Wo/Wq/Wk/Wv fp32->bf16, build bf16 mask vector (1.0/0.0).
// ---------------------------------------------------------------------------
__global__ __launch_bounds__(256) void cvt_kernel(
    const float* __restrict__ Wo, const float* __restrict__ Wq,
    const float* __restrict__ Wk, const float* __restrict__ Wv,
    const int* __restrict__ mask,
    unsigned short* __restrict__ Wob, unsigned short* __restrict__ Wqb,
    unsigned short* __restrict__ Wkb, unsigned short* __restrict__ Wvb,
    unsigned short* __restrict__ Mb)
{
    const int b = blockIdx.x, tid = threadIdx.x;
    if (b < 1024) {                       // Wo: 262144 float4
        int idx = b * 256 + tid;
        float4 w = ((const float4*)Wo)[idx];
        uint2 p; p.x = packbf2(w.x, w.y); p.y = packbf2(w.z, w.w);
        ((uint2*)Wob)[idx] = p;
    } else if (b < 1027) {                // Wq/Wk/Wv: 1024 float4 each
        const float* W = (b == 1024) ? Wq : (b == 1025) ? Wk : Wv;
        unsigned short* Wb = (b == 1024) ? Wqb : (b == 1025) ? Wkb : Wvb;
        #pragma unroll
        for (int i = 0; i < 4; ++i) {
            int idx = tid + i * 256;
            float4 w = ((const float4*)W)[idx];
            uint2 p; p.x = packbf2(w.x, w.y); p.y = packbf2(w.z, w.w);
            ((uint2*)Wb)[idx] = p;
        }
    } else {                              // Mb: NB*SEQ bf16 entries (1.0 / 0.0)
        #pragma unroll
        for (int i = 0; i < 16; ++i) {
            int idx = tid + i * 256;
            Mb[idx] = mask[idx] ? (unsigned short)0x3F80 : (unsigned short)0;
        }
    }
}

// ---------------------------------------------------------------------------
// Kernel 1: per-head QKV projection.  grid (SEQ/128, NH, 3*NB), block 256.
// Q,K out: [n][h][l][d] bf16 (Q pre-scaled by QSCALE).  V out: [n][h][d][l],
// with MASKED ROWS OF V ZEROED (so flash needs no per-score mask handling:
// numerator excludes masked keys via V=0, denominator via the mask-MFMA).
// ---------------------------------------------------------------------------
__global__ __launch_bounds__(256) void qkv_kernel(
    const float* __restrict__ Qin, const float* __restrict__ Kin,
    const float* __restrict__ Vin,
    const unsigned short* __restrict__ Wqb, const unsigned short* __restrict__ Wkb,
    const unsigned short* __restrict__ Wvb, const float* __restrict__ bq,
    const int* __restrict__ mask,
    unsigned short* __restrict__ Qp, unsigned short* __restrict__ Kp,
    unsigned short* __restrict__ Vtp)
{
    const int lt = blockIdx.x;          // 128-row l tile
    const int h  = blockIdx.y;
    const int tz = blockIdx.z;
    const int t  = tz >> 1, n = tz & 1;

    const float* X; const unsigned short* Wb;
    if (t == 0)      { X = Qin; Wb = Wqb; }
    else if (t == 1) { X = Kin; Wb = Wkb; }
    else             { X = Vin; Wb = Wvb; }

    __shared__ __align__(16) unsigned short sX[128][70];
    __shared__ __align__(16) unsigned short sT[64][136];

    const int tid = threadIdx.x, wave = tid >> 6, lane = tid & 63;
    const int ln = lane & 15, quad = lane >> 4;

    #pragma unroll
    for (int i = 0; i < 8; ++i) {
        int flat = tid + i * 256;
        int r = flat >> 4, c4 = flat & 15;
        float4 xv = *(const float4*)(X + ((size_t)(n * SEQ + lt * 128 + r)) * EMB + h * HD + c4 * 4);
        uint2 xp; xp.x = packbf2(xv.x, xv.y); xp.y = packbf2(xv.z, xv.w);
        *(uint2*)&sX[r][c4 * 4] = xp;
    }
    short8 wf0[4], wf1[4];
    #pragma unroll
    for (int nt = 0; nt < 4; ++nt) {
        wf0[nt] = *(const short8*)(Wb + (nt * 16 + ln) * HD + quad * 8);
        wf1[nt] = *(const short8*)(Wb + (nt * 16 + ln) * HD + 32 + quad * 8);
    }
    __syncthreads();

    f32x4 acc[2][4];
    #pragma unroll
    for (int set = 0; set < 2; ++set) {
        short8 af0 = *(const short8*)&sX[wave * 32 + set * 16 + ln][quad * 8];
        short8 af1 = *(const short8*)&sX[wave * 32 + set * 16 + ln][32 + quad * 8];
        #pragma unroll
        for (int nt = 0; nt < 4; ++nt) {
            f32x4 a = {0.f, 0.f, 0.f, 0.f};
            a = MFMA(af0, wf0[nt], a);
            a = MFMA(af1, wf1[nt], a);
            acc[set][nt] = a;
        }
    }

    if (t == 0) {   // bias then fold softmax scale (incl. log2e)
        #pragma unroll
        for (int nt = 0; nt < 4; ++nt) {
            float bb = bq[nt * 16 + ln];
            #pragma unroll
            for (int set = 0; set < 2; ++set)
                #pragma unroll
                for (int a = 0; a < 4; ++a)
                    acc[set][nt][a] = (acc[set][nt][a] + bb) * QSCALE;
        }
    }

    if (t < 2) {
        unsigned short* Out = (t == 0) ? Qp : Kp;
        #pragma unroll
        for (int set = 0; set < 2; ++set)
            #pragma unroll
            for (int a = 0; a < 4; ++a) {
                size_t row = (size_t)((n * NH + h) * SEQ + lt * 128 + wave * 32 + set * 16 + quad * 4 + a);
                #pragma unroll
                for (int nt = 0; nt < 4; ++nt)
                    Out[row * HD + nt * 16 + ln] = f2bf(acc[set][nt][a]);
            }
    } else {
        // zero masked V rows (l = column of V^T)
        #pragma unroll
        for (int set = 0; set < 2; ++set)
            #pragma unroll
            for (int a = 0; a < 4; ++a) {
                int l = lt * 128 + wave * 32 + set * 16 + quad * 4 + a;
                if (mask[n * SEQ + l] == 0) {
                    #pragma unroll
                    for (int nt = 0; nt < 4; ++nt) acc[set][nt][a] = 0.f;
                }
            }
        #pragma unroll
        for (int set = 0; set < 2; ++set)
            #pragma unroll
            for (int nt = 0; nt < 4; ++nt)
                #pragma unroll
                for (int a = 0; a < 4; ++a)
                    sT[nt * 16 + ln][wave * 32 + set * 16 + quad * 4 + a] = f2bf(acc[set][nt][a]);
        __syncthreads();
        #pragma unroll
        for (int i = 0; i < 4; ++i) {
            int flat = tid + i * 256;
            int r = flat >> 4, c8 = flat & 15;
            *(float4*)(Vtp + ((size_t)((n * NH + h) * HD + r)) * SEQ + lt * 128 + c8 * 8) =
                *(const float4*)&sT[r][c8 * 8];
        }
    }
}

// ---------------------------------------------------------------------------
// Kernel 2: flash attention v12 — v11 + addressing-slim K-loop.
// v11 post-mortem (65.3us): VALU issue ~27us but exp2 only ~7us -> ~19us is
// per-iteration LDS address recomputation (VGPR=68 too tight to keep the ~28
// loop-invariant swizzled offsets; runtime Kb[cur] base blocks offset-imm
// folding).  v12: (a) kt-loop unrolled by 2 with COMPILE-TIME buffer indices
// so LDS accesses become static base + offset: immediates; (b)
// __launch_bounds__(256,2) raises the VGPR cap to 256 (occupancy is 2/SIMD
// from the grid anyway; natural alloc well under cap -> no v6-style spill).
// Geometry/swizzle/mask-MFMA unchanged from v11.
// grid (NB*NH, SEQ/128), block 256 (4 waves x 32 q-rows).
// ---------------------------------------------------------------------------
__global__ __launch_bounds__(256, 2) void flash_kernel(
    const unsigned short* __restrict__ Qp, const unsigned short* __restrict__ Kp,
    const unsigned short* __restrict__ Vtp, const unsigned short* __restrict__ Mb,
    unsigned short* __restrict__ A /* [n][l][EMB] bf16 */)
{
    const int nh = blockIdx.x;
    const int qt = blockIdx.y;            // 128-row q tile
    const int n  = nh >> 4, h = nh & 15;

    const int tid  = threadIdx.x;
    const int wave = tid >> 6, lane = tid & 63;
    const int ln   = lane & 15, quad = lane >> 4;
    const int ln7  = lane & 7;

    __shared__ __align__(16) unsigned short Kb[2][64 * 64];   // 16 KiB
    __shared__ __align__(16) unsigned short Vb[2][64 * 64];   // 16 KiB
    __shared__ __align__(16) unsigned short sP[4][32 * 64];   // 16 KiB
    unsigned short* sPw = sP[wave];

    // Q B-fragments: wave owns q rows qt*128 + wave*32 + set*16 + ln
    const unsigned short* Qb = Qp + ((size_t)nh * SEQ + qt * 128 + wave * 32) * HD;
    short8 qf[2][2];
    #pragma unroll
    for (int set = 0; set < 2; ++set) {
        qf[set][0] = *(const short8*)(Qb + (set * 16 + ln) * HD + quad * 8);
        qf[set][1] = *(const short8*)(Qb + (set * 16 + ln) * HD + 32 + quad * 8);
    }

    const unsigned short* Kg = Kp  + (size_t)nh * SEQ * HD;
    const unsigned short* Vg = Vtp + (size_t)nh * HD * SEQ;
    const unsigned short* mk = Mb + n * SEQ;

    // loop-invariant swizzled LDS offsets (shorts)
    const int kx0 = ((quad)     ^ ln7) << 3;          // frag col, first half
    const int kx1 = ((quad + 4) ^ ln7) << 3;          // frag col, second half
    const int pw0 = ((quad >> 1) ^ ln7) << 3;         // sP write-chunk base (nt=0)
    const int pwb = (quad & 1) * 4;

    // staging geometry: each gload16 = 1 KiB = 8 rows of 128B.  Wave w stages
    // rows [16w, 16w+16) of both K and V.  Source chunk pre-swizzled so that
    // LDS(row, c) holds global(row, c ^ (row&7)).
    const int r8  = lane >> 3;                       // 0..7
    const int swz = ((lane & 7) ^ r8) << 3;          // shorts within row

    f32x4 o[2][4];
    #pragma unroll
    for (int s2 = 0; s2 < 2; ++s2)
        #pragma unroll
        for (int dt = 0; dt < 4; ++dt) o[s2][dt] = (f32x4){0.f, 0.f, 0.f, 0.f};
    f32x4 ol[2] = {(f32x4){0.f, 0.f, 0.f, 0.f}, (f32x4){0.f, 0.f, 0.f, 0.f}};

    #define STAGE(buf, kt_) do {                                                  \
        const unsigned short* kg_ = Kg + ((size_t)((kt_) * 64 + wave * 16 + r8)) * HD + swz; \
        const unsigned short* vg_ = Vg + ((size_t)(wave * 16 + r8)) * SEQ + (kt_) * 64 + swz; \
        unsigned short* kl_ = &Kb[buf][wave * 16 * 64];                           \
        unsigned short* vl_ = &Vb[buf][wave * 16 * 64];                           \
        gload16(kg_,            kl_);                                             \
        gload16(kg_ + 8 * HD,   kl_ + 8 * 64);                                    \
        gload16(vg_,            vl_);                                             \
        gload16(vg_ + 8 * SEQ,  vl_ + 8 * 64);                                    \
    } while (0)

    // BUF is a compile-time literal -> all LDS addresses fold to static
    // base + offset: immediates (no per-iteration address VALU).
    #define COMPUTE(BUF, KT) do {                                                 \
        short8 mf0 = *(const short8*)(mk + (KT) * 64 + quad * 8);                 \
        short8 mf1 = *(const short8*)(mk + (KT) * 64 + 32 + quad * 8);            \
        _Pragma("unroll")                                                         \
        for (int nt = 0; nt < 4; ++nt) {                                          \
            short8 kf0 = *(const short8*)&Kb[BUF][(nt * 16 + ln) * 64 + kx0];     \
            short8 kf1 = *(const short8*)&Kb[BUF][(nt * 16 + ln) * 64 + kx1];     \
            _Pragma("unroll")                                                     \
            for (int set = 0; set < 2; ++set) {                                   \
                f32x4 z = {0.f, 0.f, 0.f, 0.f};                                   \
                z = MFMA(kf0, qf[set][0], z);                                     \
                z = MFMA(kf1, qf[set][1], z);                                     \
                float p0 = EXP2(z[0]);                                            \
                float p1 = EXP2(z[1]);                                            \
                float p2 = EXP2(z[2]);                                            \
                float p3 = EXP2(z[3]);                                            \
                uint2 w; w.x = packbf2(p0, p1); w.y = packbf2(p2, p3);            \
                *(uint2*)&sPw[(set * 16 + ln) * 64 + (pw0 ^ (nt * 2 << 3)) + pwb] = w; \
            }                                                                     \
        }                                                                         \
        asm volatile("s_waitcnt lgkmcnt(0)" ::: "memory");                        \
        short8 pf[2][2];                                                          \
        _Pragma("unroll")                                                         \
        for (int set = 0; set < 2; ++set) {                                       \
            pf[set][0] = *(const short8*)&sPw[(set * 16 + ln) * 64 + kx0];        \
            pf[set][1] = *(const short8*)&sPw[(set * 16 + ln) * 64 + kx1];        \
        }                                                                         \
        _Pragma("unroll")                                                         \
        for (int set = 0; set < 2; ++set) {                                       \
            ol[set] = MFMA(pf[set][0], mf0, ol[set]);                             \
            ol[set] = MFMA(pf[set][1], mf1, ol[set]);                             \
        }                                                                         \
        _Pragma("unroll")                                                         \
        for (int dt = 0; dt < 4; ++dt) {                                          \
            short8 vf0 = *(const short8*)&Vb[BUF][(dt * 16 + ln) * 64 + kx0];     \
            short8 vf1 = *(const short8*)&Vb[BUF][(dt * 16 + ln) * 64 + kx1];     \
            _Pragma("unroll")                                                     \
            for (int set = 0; set < 2; ++set) {                                   \
                o[set][dt] = MFMA(pf[set][0], vf0, o[set][dt]);                   \
                o[set][dt] = MFMA(pf[set][1], vf1, o[set][dt]);                   \
            }                                                                     \
        }                                                                         \
    } while (0)

    STAGE(0, 0);
    __syncthreads();                       // drains vmcnt -> tile 0 ready

    #pragma unroll 1
    for (int kt = 0; kt < SEQ / 64; kt += 2) {
        STAGE(1, kt + 1);                  // async prefetch (kt+1 <= 31 always)
        COMPUTE(0, kt);
        __syncthreads();                   // prefetch landed, all buf0 reads done
        if (kt + 2 < SEQ / 64) STAGE(0, kt + 2);
        COMPUTE(1, kt + 1);
        __syncthreads();
    }
    #undef STAGE
    #undef COMPUTE

    // note: sP write chunk for nt is (nt*2 + (quad>>1)) ^ ln7; since nt*2 has
    // no overlap with (quad>>1) bits and XOR distributes, it equals
    // pw0 ^ (nt*2<<3) as used above.

    // ---- normalize own rows and write (ol[set][a] aligns with o[set][dt][a]) ----
    #pragma unroll
    for (int set = 0; set < 2; ++set)
        #pragma unroll
        for (int a = 0; a < 4; ++a) {
            float inv = 1.0f / ol[set][a];
            size_t row = (size_t)(n * SEQ + qt * 128 + wave * 32 + set * 16 + quad * 4 + a);
            #pragma unroll
            for (int dt = 0; dt < 4; ++dt)
                A[row * EMB + h * HD + dt * 16 + ln] = f2bf(o[set][dt][a] * inv);
        }
}

// ---------------------------------------------------------------------------
// Kernel 3: out = A @ Wo^T + bo, 64x128 tile.
// Was 128x128 / 256 blocks = 1 block/CU = 1 wave/SIMD (zero TLP, barrier
// drain fully exposed).  Now grid (EMB/128, NB*SEQ/64) = 512 blocks =
// 2 blocks/CU = 2 waves/SIMD; wave tile 32x64 (acc[2][4]).  LDS 27.6KB.
// ---------------------------------------------------------------------------
__global__ __launch_bounds__(256) void outproj_kernel(
    const unsigned short* __restrict__ A, const unsigned short* __restrict__ Wob,
    const float* __restrict__ bo, float* __restrict__ Out)
{
    const int ct = blockIdx.x;   // 128-col tile
    const int rt = blockIdx.y;   // 64-row tile

    const int tid  = threadIdx.x;
    const int wave = tid >> 6, lane = tid & 63;
    const int ln   = lane & 15, quad = lane >> 4;
    const int wm   = wave >> 1, wn = wave & 1;

    __shared__ __align__(16) unsigned short sA[64][72];
    __shared__ __align__(16) unsigned short sB[128][72];

    f32x4 acc[2][4];
    #pragma unroll
    for (int i = 0; i < 2; ++i)
        #pragma unroll
        for (int j = 0; j < 4; ++j) acc[i][j] = (f32x4){0.f, 0.f, 0.f, 0.f};

    for (int kc = 0; kc < EMB / 64; ++kc) {
        __syncthreads();
        #pragma unroll
        for (int i = 0; i < 2; ++i) {      // A: 64x64 = 512 float4
            int flat = tid + i * 256;
            int r = flat >> 3, c8 = flat & 7;
            *(float4*)&sA[r][c8 * 8] =
                *(const float4*)(A + (size_t)(rt * 64 + r) * EMB + kc * 64 + c8 * 8);
        }
        #pragma unroll
        for (int i = 0; i < 4; ++i) {      // B: 128x64 = 1024 float4
            int flat = tid + i * 256;
            int r = flat >> 3, c8 = flat & 7;
            *(float4*)&sB[r][c8 * 8] =
                *(const float4*)(Wob + (size_t)(ct * 128 + r) * EMB + kc * 64 + c8 * 8);
        }
        __syncthreads();

        #pragma unroll
        for (int ks = 0; ks < 2; ++ks) {
            short8 af[2], bf[4];
            #pragma unroll
            for (int i = 0; i < 2; ++i)
                af[i] = *(const short8*)&sA[wm * 32 + i * 16 + ln][ks * 32 + quad * 8];
            #pragma unroll
            for (int j = 0; j < 4; ++j)
                bf[j] = *(const short8*)&sB[wn * 64 + j * 16 + ln][ks * 32 + quad * 8];
            #pragma unroll
            for (int i = 0; i < 2; ++i)
                #pragma unroll
                for (int j = 0; j < 4; ++j)
                    acc[i][j] = MFMA(af[i], bf[j], acc[i][j]);
        }
    }

    #pragma unroll
    for (int j = 0; j < 4; ++j) {
        int col = ct * 128 + wn * 64 + j * 16 + ln;
        float bb = bo[col];
        #pragma unroll
        for (int i = 0; i < 2; ++i)
            #pragma unroll
            for (int a = 0; a < 4; ++a) {
                size_t row = (size_t)(rt * 64 + wm * 32 + i * 16 + quad * 4 + a);
                Out[row * EMB + col] = acc[i][j][a] + bb;
            }
    }
}

// ---------------------------------------------------------------------------
extern "C" void kernel_launch(void* const* d_in, const int* in_sizes, int n_in,
                              void* d_out, int out_size, void* d_ws, size_t ws_size,
                              hipStream_t stream) {
    const float* values = (const float*)d_in[0];
    const float* key_   = (const float*)d_in[1];
    const float* query  = (const float*)d_in[2];
    const int*   mask   = (const int*)d_in[3];
    const float* Wv     = (const float*)d_in[4];
    const float* Wk     = (const float*)d_in[5];
    const float* Wq     = (const float*)d_in[6];
    const float* bq     = (const float*)d_in[7];
    const float* Wo     = (const float*)d_in[8];
    const float* bo     = (const float*)d_in[9];
    float* out = (float*)d_out;

    const size_t NHLD = (size_t)NB * NH * SEQ * HD;   // 4,194,304

    unsigned short* ws = (unsigned short*)d_ws;
    unsigned short* Qp    = ws;
    unsigned short* Kp    = ws + NHLD;
    unsigned short* Vtp   = ws + 2 * NHLD;
    unsigned short* Aattn = ws + 3 * NHLD;
    unsigned short* Wob   = ws + 4 * NHLD;                  // EMB*EMB
    unsigned short* Wqb   = Wob + (size_t)EMB * EMB;
    unsigned short* Wkb   = Wqb + HD * HD;
    unsigned short* Wvb   = Wkb + HD * HD;
    unsigned short* Mb    = Wvb + HD * HD;                  // NB*SEQ bf16 mask

    cvt_kernel<<<dim3(1028), 256, 0, stream>>>(
        Wo, Wq, Wk, Wv, mask, Wob, Wqb, Wkb, Wvb, Mb);
    qkv_kernel<<<dim3(SEQ / 128, NH, 3 * NB), 256, 0, stream>>>(
        query, key_, values, Wqb, Wkb, Wvb, bq, mask, Qp, Kp, Vtp);
    flash_kernel<<<dim3(NB * NH, SEQ / 128), 256, 0, stream>>>(
        Qp, Kp, Vtp, Mb, Aattn);
    outproj_kernel<<<dim3(EMB / 128, NB * SEQ / 64), 256, 0, stream>>>(
        Aattn, Wob, bo, out);
}

// Round 9
// 185.947 us; speedup vs baseline: 1.0933x; 1.0933x over previous
//
#include <hip/hip_runtime.h>
#include <hip/hip_bf16.h>
#include <string.h>

#define NB   2
#define SEQ  2048
#define EMB  1024
#define NH   16
#define HD   64
// softmax uses exp2: fold SCALE*log2(e) into Q pre-scale
#define QSCALE 0.045084219f       // (1/32) * log2(e)

typedef __attribute__((ext_vector_type(8))) short short8;   // 8 x bf16
typedef __attribute__((ext_vector_type(4))) float f32x4;    // MFMA C/D

#define MFMA(a, b, c) __builtin_amdgcn_mfma_f32_16x16x32_bf16(a, b, c, 0, 0, 0)
#define EXP2(x) __builtin_amdgcn_exp2f(x)

__device__ __forceinline__ unsigned short f2bf(float x) {
    union { float f; unsigned u; } v; v.f = x;
    unsigned r = v.u + 0x7fffu + ((v.u >> 16) & 1u);   // RNE
    return (unsigned short)(r >> 16);
}
__device__ __forceinline__ unsigned packbf2(float a, float b) {
    __hip_bfloat162 h = __float22bfloat162_rn(make_float2(a, b));  // hw v_cvt_pk
    unsigned u; memcpy(&u, &h, 4);
    return u;
}
// async global->LDS, 16B per lane; LDS dest = uniform base + lane*16 (linear)
__device__ __forceinline__ void gload16(const void* g, void* l) {
    __builtin_amdgcn_global_load_lds(
        (const __attribute__((address_space(1))) void*)g,
        (__attribute__((address_space(3))) void*)l, 16, 0, 0);
}

// ---------------------------------------------------------------------------
// Kernel 0: convert Wo/Wq/Wk/Wv fp32->bf16, build bf16 mask vector (1.0/0.0).
// ---------------------------------------------------------------------------
__global__ __launch_bounds__(256) void cvt_kernel(
    const float* __restrict__ Wo, const float* __restrict__ Wq,
    const float* __restrict__ Wk, const float* __restrict__ Wv,
    const int* __restrict__ mask,
    unsigned short* __restrict__ Wob, unsigned short* __restrict__ Wqb,
    unsigned short* __restrict__ Wkb, unsigned short* __restrict__ Wvb,
    unsigned short* __restrict__ Mb)
{
    const int b = blockIdx.x, tid = threadIdx.x;
    if (b < 1024) {                       // Wo: 262144 float4
        int idx = b * 256 + tid;
        float4 w = ((const float4*)Wo)[idx];
        uint2 p; p.x = packbf2(w.x, w.y); p.y = packbf2(w.z, w.w);
        ((uint2*)Wob)[idx] = p;
    } else if (b < 1027) {                // Wq/Wk/Wv: 1024 float4 each
        const float* W = (b == 1024) ? Wq : (b == 1025) ? Wk : Wv;
        unsigned short* Wb = (b == 1024) ? Wqb : (b == 1025) ? Wkb : Wvb;
        #pragma unroll
        for (int i = 0; i < 4; ++i) {
            int idx = tid + i * 256;
            float4 w = ((const float4*)W)[idx];
            uint2 p; p.x = packbf2(w.x, w.y); p.y = packbf2(w.z, w.w);
            ((uint2*)Wb)[idx] = p;
        }
    } else {                              // Mb: NB*SEQ bf16 entries (1.0 / 0.0)
        #pragma unroll
        for (int i = 0; i < 16; ++i) {
            int idx = tid + i * 256;
            Mb[idx] = mask[idx] ? (unsigned short)0x3F80 : (unsigned short)0;
        }
    }
}

// ---------------------------------------------------------------------------
// Kernel 1: per-head QKV projection.  grid (SEQ/128, NH, 3*NB), block 256.
// Q,K out: [n][h][l][d] bf16 (Q pre-scaled by QSCALE).  V out: [n][h][d][l],
// with MASKED ROWS OF V ZEROED (so flash needs no per-score mask handling:
// numerator excludes masked keys via V=0, denominator via the mask-MFMA).
// ---------------------------------------------------------------------------
__global__ __launch_bounds__(256) void qkv_kernel(
    const float* __restrict__ Qin, const float* __restrict__ Kin,
    const float* __restrict__ Vin,
    const unsigned short* __restrict__ Wqb, const unsigned short* __restrict__ Wkb,
    const unsigned short* __restrict__ Wvb, const float* __restrict__ bq,
    const int* __restrict__ mask,
    unsigned short* __restrict__ Qp, unsigned short* __restrict__ Kp,
    unsigned short* __restrict__ Vtp)
{
    const int lt = blockIdx.x;          // 128-row l tile
    const int h  = blockIdx.y;
    const int tz = blockIdx.z;
    const int t  = tz >> 1, n = tz & 1;

    const float* X; const unsigned short* Wb;
    if (t == 0)      { X = Qin; Wb = Wqb; }
    else if (t == 1) { X = Kin; Wb = Wkb; }
    else             { X = Vin; Wb = Wvb; }

    __shared__ __align__(16) unsigned short sX[128][70];
    __shared__ __align__(16) unsigned short sT[64][136];

    const int tid = threadIdx.x, wave = tid >> 6, lane = tid & 63;
    const int ln = lane & 15, quad = lane >> 4;

    #pragma unroll
    for (int i = 0; i < 8; ++i) {
        int flat = tid + i * 256;
        int r = flat >> 4, c4 = flat & 15;
        float4 xv = *(const float4*)(X + ((size_t)(n * SEQ + lt * 128 + r)) * EMB + h * HD + c4 * 4);
        uint2 xp; xp.x = packbf2(xv.x, xv.y); xp.y = packbf2(xv.z, xv.w);
        *(uint2*)&sX[r][c4 * 4] = xp;
    }
    short8 wf0[4], wf1[4];
    #pragma unroll
    for (int nt = 0; nt < 4; ++nt) {
        wf0[nt] = *(const short8*)(Wb + (nt * 16 + ln) * HD + quad * 8);
        wf1[nt] = *(const short8*)(Wb + (nt * 16 + ln) * HD + 32 + quad * 8);
    }
    __syncthreads();

    f32x4 acc[2][4];
    #pragma unroll
    for (int set = 0; set < 2; ++set) {
        short8 af0 = *(const short8*)&sX[wave * 32 + set * 16 + ln][quad * 8];
        short8 af1 = *(const short8*)&sX[wave * 32 + set * 16 + ln][32 + quad * 8];
        #pragma unroll
        for (int nt = 0; nt < 4; ++nt) {
            f32x4 a = {0.f, 0.f, 0.f, 0.f};
            a = MFMA(af0, wf0[nt], a);
            a = MFMA(af1, wf1[nt], a);
            acc[set][nt] = a;
        }
    }

    if (t == 0) {   // bias then fold softmax scale (incl. log2e)
        #pragma unroll
        for (int nt = 0; nt < 4; ++nt) {
            float bb = bq[nt * 16 + ln];
            #pragma unroll
            for (int set = 0; set < 2; ++set)
                #pragma unroll
                for (int a = 0; a < 4; ++a)
                    acc[set][nt][a] = (acc[set][nt][a] + bb) * QSCALE;
        }
    }

    if (t < 2) {
        unsigned short* Out = (t == 0) ? Qp : Kp;
        #pragma unroll
        for (int set = 0; set < 2; ++set)
            #pragma unroll
            for (int a = 0; a < 4; ++a) {
                size_t row = (size_t)((n * NH + h) * SEQ + lt * 128 + wave * 32 + set * 16 + quad * 4 + a);
                #pragma unroll
                for (int nt = 0; nt < 4; ++nt)
                    Out[row * HD + nt * 16 + ln] = f2bf(acc[set][nt][a]);
            }
    } else {
        // zero masked V rows (l = column of V^T)
        #pragma unroll
        for (int set = 0; set < 2; ++set)
            #pragma unroll
            for (int a = 0; a < 4; ++a) {
                int l = lt * 128 + wave * 32 + set * 16 + quad * 4 + a;
                if (mask[n * SEQ + l] == 0) {
                    #pragma unroll
                    for (int nt = 0; nt < 4; ++nt) acc[set][nt][a] = 0.f;
                }
            }
        #pragma unroll
        for (int set = 0; set < 2; ++set)
            #pragma unroll
            for (int nt = 0; nt < 4; ++nt)
                #pragma unroll
                for (int a = 0; a < 4; ++a)
                    sT[nt * 16 + ln][wave * 32 + set * 16 + quad * 4 + a] = f2bf(acc[set][nt][a]);
        __syncthreads();
        #pragma unroll
        for (int i = 0; i < 4; ++i) {
            int flat = tid + i * 256;
            int r = flat >> 4, c8 = flat & 15;
            *(float4*)(Vtp + ((size_t)((n * NH + h) * HD + r)) * SEQ + lt * 128 + c8 * 8) =
                *(const float4*)&sT[r][c8 * 8];
        }
    }
}

// ---------------------------------------------------------------------------
// Kernel 2: flash attention v12 — v11 + addressing-slim K-loop (r8: 56.5us).
// kt-loop unrolled by 2 with compile-time buffer indices (static LDS bases +
// offset: immediates), __launch_bounds__(256,2) for VGPR headroom.
// Mask folded out of the score chain (V rows zeroed in qkv; denominator via
// mask-MFMA).  K/V double-buffered in LDS via pre-swizzled global_load_lds.
// grid (NB*NH, SEQ/128), block 256 (4 waves x 32 q-rows).
// ---------------------------------------------------------------------------
__global__ __launch_bounds__(256, 2) void flash_kernel(
    const unsigned short* __restrict__ Qp, const unsigned short* __restrict__ Kp,
    const unsigned short* __restrict__ Vtp, const unsigned short* __restrict__ Mb,
    unsigned short* __restrict__ A /* [n][l][EMB] bf16 */)
{
    const int nh = blockIdx.x;
    const int qt = blockIdx.y;            // 128-row q tile
    const int n  = nh >> 4, h = nh & 15;

    const int tid  = threadIdx.x;
    const int wave = tid >> 6, lane = tid & 63;
    const int ln   = lane & 15, quad = lane >> 4;
    const int ln7  = lane & 7;

    __shared__ __align__(16) unsigned short Kb[2][64 * 64];   // 16 KiB
    __shared__ __align__(16) unsigned short Vb[2][64 * 64];   // 16 KiB
    __shared__ __align__(16) unsigned short sP[4][32 * 64];   // 16 KiB
    unsigned short* sPw = sP[wave];

    // Q B-fragments: wave owns q rows qt*128 + wave*32 + set*16 + ln
    const unsigned short* Qb = Qp + ((size_t)nh * SEQ + qt * 128 + wave * 32) * HD;
    short8 qf[2][2];
    #pragma unroll
    for (int set = 0; set < 2; ++set) {
        qf[set][0] = *(const short8*)(Qb + (set * 16 + ln) * HD + quad * 8);
        qf[set][1] = *(const short8*)(Qb + (set * 16 + ln) * HD + 32 + quad * 8);
    }

    const unsigned short* Kg = Kp  + (size_t)nh * SEQ * HD;
    const unsigned short* Vg = Vtp + (size_t)nh * HD * SEQ;
    const unsigned short* mk = Mb + n * SEQ;

    // loop-invariant swizzled LDS offsets (shorts)
    const int kx0 = ((quad)     ^ ln7) << 3;          // frag col, first half
    const int kx1 = ((quad + 4) ^ ln7) << 3;          // frag col, second half
    const int pw0 = ((quad >> 1) ^ ln7) << 3;         // sP write-chunk base (nt=0)
    const int pwb = (quad & 1) * 4;

    // staging geometry: each gload16 = 1 KiB = 8 rows of 128B.  Wave w stages
    // rows [16w, 16w+16) of both K and V.  Source chunk pre-swizzled so that
    // LDS(row, c) holds global(row, c ^ (row&7)).
    const int r8  = lane >> 3;                       // 0..7
    const int swz = ((lane & 7) ^ r8) << 3;          // shorts within row

    f32x4 o[2][4];
    #pragma unroll
    for (int s2 = 0; s2 < 2; ++s2)
        #pragma unroll
        for (int dt = 0; dt < 4; ++dt) o[s2][dt] = (f32x4){0.f, 0.f, 0.f, 0.f};
    f32x4 ol[2] = {(f32x4){0.f, 0.f, 0.f, 0.f}, (f32x4){0.f, 0.f, 0.f, 0.f}};

    #define STAGE(buf, kt_) do {                                                  \
        const unsigned short* kg_ = Kg + ((size_t)((kt_) * 64 + wave * 16 + r8)) * HD + swz; \
        const unsigned short* vg_ = Vg + ((size_t)(wave * 16 + r8)) * SEQ + (kt_) * 64 + swz; \
        unsigned short* kl_ = &Kb[buf][wave * 16 * 64];                           \
        unsigned short* vl_ = &Vb[buf][wave * 16 * 64];                           \
        gload16(kg_,            kl_);                                             \
        gload16(kg_ + 8 * HD,   kl_ + 8 * 64);                                    \
        gload16(vg_,            vl_);                                             \
        gload16(vg_ + 8 * SEQ,  vl_ + 8 * 64);                                    \
    } while (0)

    // BUF is a compile-time literal -> all LDS addresses fold to static
    // base + offset: immediates (no per-iteration address VALU).
    #define COMPUTE(BUF, KT) do {                                                 \
        short8 mf0 = *(const short8*)(mk + (KT) * 64 + quad * 8);                 \
        short8 mf1 = *(const short8*)(mk + (KT) * 64 + 32 + quad * 8);            \
        _Pragma("unroll")                                                         \
        for (int nt = 0; nt < 4; ++nt) {                                          \
            short8 kf0 = *(const short8*)&Kb[BUF][(nt * 16 + ln) * 64 + kx0];     \
            short8 kf1 = *(const short8*)&Kb[BUF][(nt * 16 + ln) * 64 + kx1];     \
            _Pragma("unroll")                                                     \
            for (int set = 0; set < 2; ++set) {                                   \
                f32x4 z = {0.f, 0.f, 0.f, 0.f};                                   \
                z = MFMA(kf0, qf[set][0], z);                                     \
                z = MFMA(kf1, qf[set][1], z);                                     \
                float p0 = EXP2(z[0]);                                            \
                float p1 = EXP2(z[1]);                                            \
                float p2 = EXP2(z[2]);                                            \
                float p3 = EXP2(z[3]);                                            \
                uint2 w; w.x = packbf2(p0, p1); w.y = packbf2(p2, p3);            \
                *(uint2*)&sPw[(set * 16 + ln) * 64 + (pw0 ^ (nt * 2 << 3)) + pwb] = w; \
            }                                                                     \
        }                                                                         \
        asm volatile("s_waitcnt lgkmcnt(0)" ::: "memory");                        \
        short8 pf[2][2];                                                          \
        _Pragma("unroll")                                                         \
        for (int set = 0; set < 2; ++set) {                                       \
            pf[set][0] = *(const short8*)&sPw[(set * 16 + ln) * 64 + kx0];        \
            pf[set][1] = *(const short8*)&sPw[(set * 16 + ln) * 64 + kx1];        \
        }                                                                         \
        _Pragma("unroll")                                                         \
        for (int set = 0; set < 2; ++set) {                                       \
            ol[set] = MFMA(pf[set][0], mf0, ol[set]);                             \
            ol[set] = MFMA(pf[set][1], mf1, ol[set]);                             \
        }                                                                         \
        _Pragma("unroll")                                                         \
        for (int dt = 0; dt < 4; ++dt) {                                          \
            short8 vf0 = *(const short8*)&Vb[BUF][(dt * 16 + ln) * 64 + kx0];     \
            short8 vf1 = *(const short8*)&Vb[BUF][(dt * 16 + ln) * 64 + kx1];     \
            _Pragma("unroll")                                                     \
            for (int set = 0; set < 2; ++set) {                                   \
                o[set][dt] = MFMA(pf[set][0], vf0, o[set][dt]);                   \
                o[set][dt] = MFMA(pf[set][1], vf1, o[set][dt]);                   \
            }                                                                     \
        }                                                                         \
    } while (0)

    STAGE(0, 0);
    __syncthreads();                       // drains vmcnt -> tile 0 ready

    #pragma unroll 1
    for (int kt = 0; kt < SEQ / 64; kt += 2) {
        STAGE(1, kt + 1);                  // async prefetch (kt+1 <= 31 always)
        COMPUTE(0, kt);
        __syncthreads();                   // prefetch landed, all buf0 reads done
        if (kt + 2 < SEQ / 64) STAGE(0, kt + 2);
        COMPUTE(1, kt + 1);
        __syncthreads();
    }
    #undef STAGE
    #undef COMPUTE

    // ---- normalize own rows and write (ol[set][a] aligns with o[set][dt][a]) ----
    #pragma unroll
    for (int set = 0; set < 2; ++set)
        #pragma unroll
        for (int a = 0; a < 4; ++a) {
            float inv = 1.0f / ol[set][a];
            size_t row = (size_t)(n * SEQ + qt * 128 + wave * 32 + set * 16 + quad * 4 + a);
            #pragma unroll
            for (int dt = 0; dt < 4; ++dt)
                A[row * EMB + h * HD + dt * 16 + ln] = f2bf(o[set][dt][a] * inv);
        }
}

// ---------------------------------------------------------------------------
// Kernel 3: out = A @ Wo^T + bo, 128x128 tile (m93 structure).
// REVERTED to the r7 version: the r8 64x128 retile cost ~19us (non-flash pot
// 127 -> 147us) — halving the row-tile doubled per-block Wob staging traffic
// and barrier count; B-reuse in the 128x128 tile is worth more than the
// extra wave of TLP.
// grid (EMB/128, NB*SEQ/128), block 256 (2x2 waves of 64x64).
// ---------------------------------------------------------------------------
__global__ __launch_bounds__(256) void outproj_kernel(
    const unsigned short* __restrict__ A, const unsigned short* __restrict__ Wob,
    const float* __restrict__ bo, float* __restrict__ Out)
{
    const int ct = blockIdx.x;   // 128-col tile
    const int rt = blockIdx.y;   // 128-row tile

    const int tid  = threadIdx.x;
    const int wave = tid >> 6, lane = tid & 63;
    const int ln   = lane & 15, quad = lane >> 4;
    const int wm   = wave >> 1, wn = wave & 1;

    __shared__ __align__(16) unsigned short sA[128][72];
    __shared__ __align__(16) unsigned short sB[128][72];

    f32x4 acc[4][4];
    #pragma unroll
    for (int i = 0; i < 4; ++i)
        #pragma unroll
        for (int j = 0; j < 4; ++j) acc[i][j] = (f32x4){0.f, 0.f, 0.f, 0.f};

    for (int kc = 0; kc < EMB / 64; ++kc) {
        __syncthreads();
        #pragma unroll
        for (int i = 0; i < 4; ++i) {
            int flat = tid + i * 256;          // 0..1023, 8-bf16 groups
            int r = flat >> 3, c8 = flat & 7;
            *(float4*)&sA[r][c8 * 8] =
                *(const float4*)(A + (size_t)(rt * 128 + r) * EMB + kc * 64 + c8 * 8);
            *(float4*)&sB[r][c8 * 8] =
                *(const float4*)(Wob + (size_t)(ct * 128 + r) * EMB + kc * 64 + c8 * 8);
        }
        __syncthreads();

        #pragma unroll
        for (int ks = 0; ks < 2; ++ks) {
            short8 af[4], bf[4];
            #pragma unroll
            for (int i = 0; i < 4; ++i)
                af[i] = *(const short8*)&sA[wm * 64 + i * 16 + ln][ks * 32 + quad * 8];
            #pragma unroll
            for (int j = 0; j < 4; ++j)
                bf[j] = *(const short8*)&sB[wn * 64 + j * 16 + ln][ks * 32 + quad * 8];
            #pragma unroll
            for (int i = 0; i < 4; ++i)
                #pragma unroll
                for (int j = 0; j < 4; ++j)
                    acc[i][j] = MFMA(af[i], bf[j], acc[i][j]);
        }
    }

    #pragma unroll
    for (int j = 0; j < 4; ++j) {
        int col = ct * 128 + wn * 64 + j * 16 + ln;
        float bb = bo[col];
        #pragma unroll
        for (int i = 0; i < 4; ++i)
            #pragma unroll
            for (int a = 0; a < 4; ++a) {
                size_t row = (size_t)(rt * 128 + wm * 64 + i * 16 + quad * 4 + a);
                Out[row * EMB + col] = acc[i][j][a] + bb;
            }
    }
}

// ---------------------------------------------------------------------------
extern "C" void kernel_launch(void* const* d_in, const int* in_sizes, int n_in,
                              void* d_out, int out_size, void* d_ws, size_t ws_size,
                              hipStream_t stream) {
    const float* values = (const float*)d_in[0];
    const float* key_   = (const float*)d_in[1];
    const float* query  = (const float*)d_in[2];
    const int*   mask   = (const int*)d_in[3];
    const float* Wv     = (const float*)d_in[4];
    const float* Wk     = (const float*)d_in[5];
    const float* Wq     = (const float*)d_in[6];
    const float* bq     = (const float*)d_in[7];
    const float* Wo     = (const float*)d_in[8];
    const float* bo     = (const float*)d_in[9];
    float* out = (float*)d_out;

    const size_t NHLD = (size_t)NB * NH * SEQ * HD;   // 4,194,304

    unsigned short* ws = (unsigned short*)d_ws;
    unsigned short* Qp    = ws;
    unsigned short* Kp    = ws + NHLD;
    unsigned short* Vtp   = ws + 2 * NHLD;
    unsigned short* Aattn = ws + 3 * NHLD;
    unsigned short* Wob   = ws + 4 * NHLD;                  // EMB*EMB
    unsigned short* Wqb   = Wob + (size_t)EMB * EMB;
    unsigned short* Wkb   = Wqb + HD * HD;
    unsigned short* Wvb   = Wkb + HD * HD;
    unsigned short* Mb    = Wvb + HD * HD;                  // NB*SEQ bf16 mask

    cvt_kernel<<<dim3(1028), 256, 0, stream>>>(
        Wo, Wq, Wk, Wv, mask, Wob, Wqb, Wkb, Wvb, Mb);
    qkv_kernel<<<dim3(SEQ / 128, NH, 3 * NB), 256, 0, stream>>>(
        query, key_, values, Wqb, Wkb, Wvb, bq, mask, Qp, Kp, Vtp);
    flash_kernel<<<dim3(NB * NH, SEQ / 128), 256, 0, stream>>>(
        Qp, Kp, Vtp, Mb, Aattn);
    outproj_kernel<<<dim3(EMB / 128, NB * SEQ / 128), 256, 0, stream>>>(
        Aattn, Wob, bo, out);
}

// Round 10
// 185.445 us; speedup vs baseline: 1.0962x; 1.0027x over previous
//
#include <hip/hip_runtime.h>
#include <hip/hip_bf16.h>
#include <string.h>

#define NB   2
#define SEQ  2048
#define EMB  1024
#define NH   16
#define HD   64
// softmax uses exp2: fold SCALE*log2(e) into Q pre-scale
#define QSCALE 0.045084219f       // (1/32) * log2(e)

typedef __attribute__((ext_vector_type(8))) short short8;   // 8 x bf16
typedef __attribute__((ext_vector_type(4))) float f32x4;    // MFMA C/D

#define MFMA(a, b, c) __builtin_amdgcn_mfma_f32_16x16x32_bf16(a, b, c, 0, 0, 0)
#define EXP2(x) __builtin_amdgcn_exp2f(x)

__device__ __forceinline__ unsigned short f2bf(float x) {
    union { float f; unsigned u; } v; v.f = x;
    unsigned r = v.u + 0x7fffu + ((v.u >> 16) & 1u);   // RNE
    return (unsigned short)(r >> 16);
}
__device__ __forceinline__ unsigned packbf2(float a, float b) {
    __hip_bfloat162 h = __float22bfloat162_rn(make_float2(a, b));  // hw v_cvt_pk
    unsigned u; memcpy(&u, &h, 4);
    return u;
}
// async global->LDS, 16B per lane; LDS dest = uniform base + lane*16 (linear)
__device__ __forceinline__ void gload16(const void* g, void* l) {
    __builtin_amdgcn_global_load_lds(
        (const __attribute__((address_space(1))) void*)g,
        (__attribute__((address_space(3))) void*)l, 16, 0, 0);
}

// ---------------------------------------------------------------------------
// Kernel 0: convert Wo/Wq/Wk/Wv fp32->bf16, build bf16 mask vector (1.0/0.0).
// ---------------------------------------------------------------------------
__global__ __launch_bounds__(256) void cvt_kernel(
    const float* __restrict__ Wo, const float* __restrict__ Wq,
    const float* __restrict__ Wk, const float* __restrict__ Wv,
    const int* __restrict__ mask,
    unsigned short* __restrict__ Wob, unsigned short* __restrict__ Wqb,
    unsigned short* __restrict__ Wkb, unsigned short* __restrict__ Wvb,
    unsigned short* __restrict__ Mb)
{
    const int b = blockIdx.x, tid = threadIdx.x;
    if (b < 1024) {                       // Wo: 262144 float4
        int idx = b * 256 + tid;
        float4 w = ((const float4*)Wo)[idx];
        uint2 p; p.x = packbf2(w.x, w.y); p.y = packbf2(w.z, w.w);
        ((uint2*)Wob)[idx] = p;
    } else if (b < 1027) {                // Wq/Wk/Wv: 1024 float4 each
        const float* W = (b == 1024) ? Wq : (b == 1025) ? Wk : Wv;
        unsigned short* Wb = (b == 1024) ? Wqb : (b == 1025) ? Wkb : Wvb;
        #pragma unroll
        for (int i = 0; i < 4; ++i) {
            int idx = tid + i * 256;
            float4 w = ((const float4*)W)[idx];
            uint2 p; p.x = packbf2(w.x, w.y); p.y = packbf2(w.z, w.w);
            ((uint2*)Wb)[idx] = p;
        }
    } else {                              // Mb: NB*SEQ bf16 entries (1.0 / 0.0)
        #pragma unroll
        for (int i = 0; i < 16; ++i) {
            int idx = tid + i * 256;
            Mb[idx] = mask[idx] ? (unsigned short)0x3F80 : (unsigned short)0;
        }
    }
}

// ---------------------------------------------------------------------------
// Kernel 1: per-head QKV projection.  grid (SEQ/128, NH, 3*NB), block 256.
// Q,K out: [n][h][l][d] bf16 (Q pre-scaled by QSCALE).  V out: [n][h][d][l],
// with MASKED ROWS OF V ZEROED (so flash needs no per-score mask handling:
// numerator excludes masked keys via V=0, denominator via the mask-MFMA).
// ---------------------------------------------------------------------------
__global__ __launch_bounds__(256) void qkv_kernel(
    const float* __restrict__ Qin, const float* __restrict__ Kin,
    const float* __restrict__ Vin,
    const unsigned short* __restrict__ Wqb, const unsigned short* __restrict__ Wkb,
    const unsigned short* __restrict__ Wvb, const float* __restrict__ bq,
    const int* __restrict__ mask,
    unsigned short* __restrict__ Qp, unsigned short* __restrict__ Kp,
    unsigned short* __restrict__ Vtp)
{
    const int lt = blockIdx.x;          // 128-row l tile
    const int h  = blockIdx.y;
    const int tz = blockIdx.z;
    const int t  = tz >> 1, n = tz & 1;

    const float* X; const unsigned short* Wb;
    if (t == 0)      { X = Qin; Wb = Wqb; }
    else if (t == 1) { X = Kin; Wb = Wkb; }
    else             { X = Vin; Wb = Wvb; }

    __shared__ __align__(16) unsigned short sX[128][70];
    __shared__ __align__(16) unsigned short sT[64][136];

    const int tid = threadIdx.x, wave = tid >> 6, lane = tid & 63;
    const int ln = lane & 15, quad = lane >> 4;

    #pragma unroll
    for (int i = 0; i < 8; ++i) {
        int flat = tid + i * 256;
        int r = flat >> 4, c4 = flat & 15;
        float4 xv = *(const float4*)(X + ((size_t)(n * SEQ + lt * 128 + r)) * EMB + h * HD + c4 * 4);
        uint2 xp; xp.x = packbf2(xv.x, xv.y); xp.y = packbf2(xv.z, xv.w);
        *(uint2*)&sX[r][c4 * 4] = xp;
    }
    short8 wf0[4], wf1[4];
    #pragma unroll
    for (int nt = 0; nt < 4; ++nt) {
        wf0[nt] = *(const short8*)(Wb + (nt * 16 + ln) * HD + quad * 8);
        wf1[nt] = *(const short8*)(Wb + (nt * 16 + ln) * HD + 32 + quad * 8);
    }
    __syncthreads();

    f32x4 acc[2][4];
    #pragma unroll
    for (int set = 0; set < 2; ++set) {
        short8 af0 = *(const short8*)&sX[wave * 32 + set * 16 + ln][quad * 8];
        short8 af1 = *(const short8*)&sX[wave * 32 + set * 16 + ln][32 + quad * 8];
        #pragma unroll
        for (int nt = 0; nt < 4; ++nt) {
            f32x4 a = {0.f, 0.f, 0.f, 0.f};
            a = MFMA(af0, wf0[nt], a);
            a = MFMA(af1, wf1[nt], a);
            acc[set][nt] = a;
        }
    }

    if (t == 0) {   // bias then fold softmax scale (incl. log2e)
        #pragma unroll
        for (int nt = 0; nt < 4; ++nt) {
            float bb = bq[nt * 16 + ln];
            #pragma unroll
            for (int set = 0; set < 2; ++set)
                #pragma unroll
                for (int a = 0; a < 4; ++a)
                    acc[set][nt][a] = (acc[set][nt][a] + bb) * QSCALE;
        }
    }

    if (t < 2) {
        unsigned short* Out = (t == 0) ? Qp : Kp;
        #pragma unroll
        for (int set = 0; set < 2; ++set)
            #pragma unroll
            for (int a = 0; a < 4; ++a) {
                size_t row = (size_t)((n * NH + h) * SEQ + lt * 128 + wave * 32 + set * 16 + quad * 4 + a);
                #pragma unroll
                for (int nt = 0; nt < 4; ++nt)
                    Out[row * HD + nt * 16 + ln] = f2bf(acc[set][nt][a]);
            }
    } else {
        // zero masked V rows (l = column of V^T)
        #pragma unroll
        for (int set = 0; set < 2; ++set)
            #pragma unroll
            for (int a = 0; a < 4; ++a) {
                int l = lt * 128 + wave * 32 + set * 16 + quad * 4 + a;
                if (mask[n * SEQ + l] == 0) {
                    #pragma unroll
                    for (int nt = 0; nt < 4; ++nt) acc[set][nt][a] = 0.f;
                }
            }
        #pragma unroll
        for (int set = 0; set < 2; ++set)
            #pragma unroll
            for (int nt = 0; nt < 4; ++nt)
                #pragma unroll
                for (int a = 0; a < 4; ++a)
                    sT[nt * 16 + ln][wave * 32 + set * 16 + quad * 4 + a] = f2bf(acc[set][nt][a]);
        __syncthreads();
        #pragma unroll
        for (int i = 0; i < 4; ++i) {
            int flat = tid + i * 256;
            int r = flat >> 4, c8 = flat & 15;
            *(float4*)(Vtp + ((size_t)((n * NH + h) * HD + r)) * SEQ + lt * 128 + c8 * 8) =
                *(const float4*)&sT[r][c8 * 8];
        }
    }
}

// ---------------------------------------------------------------------------
// Kernel 2: flash attention v12 — unchanged from r9 (57.7us).
// kt-loop unrolled by 2 with compile-time buffer indices (static LDS bases +
// offset: immediates), __launch_bounds__(256,2) for VGPR headroom.
// Mask folded out of the score chain (V rows zeroed in qkv; denominator via
// mask-MFMA).  K/V double-buffered in LDS via pre-swizzled global_load_lds.
// grid (NB*NH, SEQ/128), block 256 (4 waves x 32 q-rows).
// ---------------------------------------------------------------------------
__global__ __launch_bounds__(256, 2) void flash_kernel(
    const unsigned short* __restrict__ Qp, const unsigned short* __restrict__ Kp,
    const unsigned short* __restrict__ Vtp, const unsigned short* __restrict__ Mb,
    unsigned short* __restrict__ A /* [n][l][EMB] bf16 */)
{
    const int nh = blockIdx.x;
    const int qt = blockIdx.y;            // 128-row q tile
    const int n  = nh >> 4, h = nh & 15;

    const int tid  = threadIdx.x;
    const int wave = tid >> 6, lane = tid & 63;
    const int ln   = lane & 15, quad = lane >> 4;
    const int ln7  = lane & 7;

    __shared__ __align__(16) unsigned short Kb[2][64 * 64];   // 16 KiB
    __shared__ __align__(16) unsigned short Vb[2][64 * 64];   // 16 KiB
    __shared__ __align__(16) unsigned short sP[4][32 * 64];   // 16 KiB
    unsigned short* sPw = sP[wave];

    // Q B-fragments: wave owns q rows qt*128 + wave*32 + set*16 + ln
    const unsigned short* Qb = Qp + ((size_t)nh * SEQ + qt * 128 + wave * 32) * HD;
    short8 qf[2][2];
    #pragma unroll
    for (int set = 0; set < 2; ++set) {
        qf[set][0] = *(const short8*)(Qb + (set * 16 + ln) * HD + quad * 8);
        qf[set][1] = *(const short8*)(Qb + (set * 16 + ln) * HD + 32 + quad * 8);
    }

    const unsigned short* Kg = Kp  + (size_t)nh * SEQ * HD;
    const unsigned short* Vg = Vtp + (size_t)nh * HD * SEQ;
    const unsigned short* mk = Mb + n * SEQ;

    // loop-invariant swizzled LDS offsets (shorts)
    const int kx0 = ((quad)     ^ ln7) << 3;          // frag col, first half
    const int kx1 = ((quad + 4) ^ ln7) << 3;          // frag col, second half
    const int pw0 = ((quad >> 1) ^ ln7) << 3;         // sP write-chunk base (nt=0)
    const int pwb = (quad & 1) * 4;

    // staging geometry: each gload16 = 1 KiB = 8 rows of 128B.  Wave w stages
    // rows [16w, 16w+16) of both K and V.  Source chunk pre-swizzled so that
    // LDS(row, c) holds global(row, c ^ (row&7)).
    const int r8  = lane >> 3;                       // 0..7
    const int swz = ((lane & 7) ^ r8) << 3;          // shorts within row

    f32x4 o[2][4];
    #pragma unroll
    for (int s2 = 0; s2 < 2; ++s2)
        #pragma unroll
        for (int dt = 0; dt < 4; ++dt) o[s2][dt] = (f32x4){0.f, 0.f, 0.f, 0.f};
    f32x4 ol[2] = {(f32x4){0.f, 0.f, 0.f, 0.f}, (f32x4){0.f, 0.f, 0.f, 0.f}};

    #define STAGE(buf, kt_) do {                                                  \
        const unsigned short* kg_ = Kg + ((size_t)((kt_) * 64 + wave * 16 + r8)) * HD + swz; \
        const unsigned short* vg_ = Vg + ((size_t)(wave * 16 + r8)) * SEQ + (kt_) * 64 + swz; \
        unsigned short* kl_ = &Kb[buf][wave * 16 * 64];                           \
        unsigned short* vl_ = &Vb[buf][wave * 16 * 64];                           \
        gload16(kg_,            kl_);                                             \
        gload16(kg_ + 8 * HD,   kl_ + 8 * 64);                                    \
        gload16(vg_,            vl_);                                             \
        gload16(vg_ + 8 * SEQ,  vl_ + 8 * 64);                                    \
    } while (0)

    // BUF is a compile-time literal -> all LDS addresses fold to static
    // base + offset: immediates (no per-iteration address VALU).
    #define COMPUTE(BUF, KT) do {                                                 \
        short8 mf0 = *(const short8*)(mk + (KT) * 64 + quad * 8);                 \
        short8 mf1 = *(const short8*)(mk + (KT) * 64 + 32 + quad * 8);            \
        _Pragma("unroll")                                                         \
        for (int nt = 0; nt < 4; ++nt) {                                          \
            short8 kf0 = *(const short8*)&Kb[BUF][(nt * 16 + ln) * 64 + kx0];     \
            short8 kf1 = *(const short8*)&Kb[BUF][(nt * 16 + ln) * 64 + kx1];     \
            _Pragma("unroll")                                                     \
            for (int set = 0; set < 2; ++set) {                                   \
                f32x4 z = {0.f, 0.f, 0.f, 0.f};                                   \
                z = MFMA(kf0, qf[set][0], z);                                     \
                z = MFMA(kf1, qf[set][1], z);                                     \
                float p0 = EXP2(z[0]);                                            \
                float p1 = EXP2(z[1]);                                            \
                float p2 = EXP2(z[2]);                                            \
                float p3 = EXP2(z[3]);                                            \
                uint2 w; w.x = packbf2(p0, p1); w.y = packbf2(p2, p3);            \
                *(uint2*)&sPw[(set * 16 + ln) * 64 + (pw0 ^ (nt * 2 << 3)) + pwb] = w; \
            }                                                                     \
        }                                                                         \
        asm volatile("s_waitcnt lgkmcnt(0)" ::: "memory");                        \
        short8 pf[2][2];                                                          \
        _Pragma("unroll")                                                         \
        for (int set = 0; set < 2; ++set) {                                       \
            pf[set][0] = *(const short8*)&sPw[(set * 16 + ln) * 64 + kx0];        \
            pf[set][1] = *(const short8*)&sPw[(set * 16 + ln) * 64 + kx1];        \
        }                                                                         \
        _Pragma("unroll")                                                         \
        for (int set = 0; set < 2; ++set) {                                       \
            ol[set] = MFMA(pf[set][0], mf0, ol[set]);                             \
            ol[set] = MFMA(pf[set][1], mf1, ol[set]);                             \
        }                                                                         \
        _Pragma("unroll")                                                         \
        for (int dt = 0; dt < 4; ++dt) {                                          \
            short8 vf0 = *(const short8*)&Vb[BUF][(dt * 16 + ln) * 64 + kx0];     \
            short8 vf1 = *(const short8*)&Vb[BUF][(dt * 16 + ln) * 64 + kx1];     \
            _Pragma("unroll")                                                     \
            for (int set = 0; set < 2; ++set) {                                   \
                o[set][dt] = MFMA(pf[set][0], vf0, o[set][dt]);                   \
                o[set][dt] = MFMA(pf[set][1], vf1, o[set][dt]);                   \
            }                                                                     \
        }                                                                         \
    } while (0)

    STAGE(0, 0);
    __syncthreads();                       // drains vmcnt -> tile 0 ready

    #pragma unroll 1
    for (int kt = 0; kt < SEQ / 64; kt += 2) {
        STAGE(1, kt + 1);                  // async prefetch (kt+1 <= 31 always)
        COMPUTE(0, kt);
        __syncthreads();                   // prefetch landed, all buf0 reads done
        if (kt + 2 < SEQ / 64) STAGE(0, kt + 2);
        COMPUTE(1, kt + 1);
        __syncthreads();
    }
    #undef STAGE
    #undef COMPUTE

    // ---- normalize own rows and write (ol[set][a] aligns with o[set][dt][a]) ----
    #pragma unroll
    for (int set = 0; set < 2; ++set)
        #pragma unroll
        for (int a = 0; a < 4; ++a) {
            float inv = 1.0f / ol[set][a];
            size_t row = (size_t)(n * SEQ + qt * 128 + wave * 32 + set * 16 + quad * 4 + a);
            #pragma unroll
            for (int dt = 0; dt < 4; ++dt)
                A[row * EMB + h * HD + dt * 16 + ln] = f2bf(o[set][dt][a] * inv);
        }
}

// ---------------------------------------------------------------------------
// Kernel 3: out = A @ Wo^T + bo, 128x128 tile — v2: flash-style pipeline.
// r8 showed smaller tiles lose (B-reuse > TLP); r9 restored 128x128 at
// ~1 block/CU but with sync VGPR-roundtrip staging and 2 exposed barriers
// per kc (pre-m97 structure).  v2 keeps the exact 128x128 tile + fragment
// mapping and swaps the staging for the flash-proven async pipeline:
//   - global_load_lds(16B) direct to LDS, A+B double-buffered (64 KB),
//   - one barrier per kc with next tile's loads in flight across COMPUTE,
//   - kc unrolled x2 for compile-time buffer indices (static LDS offsets),
//   - XOR-chunk swizzle: LDS(row,c)=global(row, c^(row&7)) via pre-swizzled
//     source; ds_read applies the same XOR (row&7 == ln7, same as flash).
// grid (EMB/128, NB*SEQ/128), block 256 (2x2 waves of 64x64).
// ---------------------------------------------------------------------------
__global__ __launch_bounds__(256) void outproj_kernel(
    const unsigned short* __restrict__ A, const unsigned short* __restrict__ Wob,
    const float* __restrict__ bo, float* __restrict__ Out)
{
    const int ct = blockIdx.x;   // 128-col tile
    const int rt = blockIdx.y;   // 128-row tile

    const int tid  = threadIdx.x;
    const int wave = tid >> 6, lane = tid & 63;
    const int ln   = lane & 15, quad = lane >> 4;
    const int ln7  = lane & 7;
    const int wm   = wave >> 1, wn = wave & 1;

    __shared__ __align__(16) unsigned short sA[2][128 * 64];   // 16 KiB each
    __shared__ __align__(16) unsigned short sB[2][128 * 64];

    // staging: each gload16 = 1 KiB = 8 rows of 128B.  Wave w stages rows
    // [32w, 32w+32) of A and B (4 gload16 each).  Source pre-swizzled:
    // lane l fetches chunk (l&7)^(l>>3) so LDS(row,c)=global(row,c^(row&7)).
    const int r8  = lane >> 3;                       // 0..7
    const int swz = ((lane & 7) ^ r8) << 3;          // shorts within row

    f32x4 acc[4][4];
    #pragma unroll
    for (int i = 0; i < 4; ++i)
        #pragma unroll
        for (int j = 0; j < 4; ++j) acc[i][j] = (f32x4){0.f, 0.f, 0.f, 0.f};

    #define STAGE(buf, kc_) do {                                                  \
        _Pragma("unroll")                                                         \
        for (int sub = 0; sub < 4; ++sub) {                                       \
            int rloc = wave * 32 + sub * 8;                                       \
            gload16(A   + (size_t)(rt * 128 + rloc + r8) * EMB + (kc_) * 64 + swz,\
                    &sA[buf][rloc * 64]);                                         \
            gload16(Wob + (size_t)(ct * 128 + rloc + r8) * EMB + (kc_) * 64 + swz,\
                    &sB[buf][rloc * 64]);                                         \
        }                                                                         \
    } while (0)

    #define COMPUTE(BUF) do {                                                     \
        _Pragma("unroll")                                                         \
        for (int ks = 0; ks < 2; ++ks) {                                          \
            short8 af[4], bf[4];                                                  \
            _Pragma("unroll")                                                     \
            for (int i = 0; i < 4; ++i)                                           \
                af[i] = *(const short8*)&sA[BUF][(wm * 64 + i * 16 + ln) * 64     \
                                                + (((ks * 4 + quad) ^ ln7) << 3)];\
            _Pragma("unroll")                                                     \
            for (int j = 0; j < 4; ++j)                                           \
                bf[j] = *(const short8*)&sB[BUF][(wn * 64 + j * 16 + ln) * 64     \
                                                + (((ks * 4 + quad) ^ ln7) << 3)];\
            _Pragma("unroll")                                                     \
            for (int i = 0; i < 4; ++i)                                           \
                _Pragma("unroll")                                                 \
                for (int j = 0; j < 4; ++j)                                       \
                    acc[i][j] = MFMA(af[i], bf[j], acc[i][j]);                    \
        }                                                                         \
    } while (0)

    STAGE(0, 0);
    __syncthreads();                       // drains vmcnt -> tile 0 ready

    #pragma unroll 1
    for (int kc = 0; kc < EMB / 64; kc += 2) {
        STAGE(1, kc + 1);                  // async prefetch
        COMPUTE(0);
        __syncthreads();                   // prefetch landed, all buf0 reads done
        if (kc + 2 < EMB / 64) STAGE(0, kc + 2);
        COMPUTE(1);
        __syncthreads();
    }
    #undef STAGE
    #undef COMPUTE

    #pragma unroll
    for (int j = 0; j < 4; ++j) {
        int col = ct * 128 + wn * 64 + j * 16 + ln;
        float bb = bo[col];
        #pragma unroll
        for (int i = 0; i < 4; ++i)
            #pragma unroll
            for (int a = 0; a < 4; ++a) {
                size_t row = (size_t)(rt * 128 + wm * 64 + i * 16 + quad * 4 + a);
                Out[row * EMB + col] = acc[i][j][a] + bb;
            }
    }
}

// ---------------------------------------------------------------------------
extern "C" void kernel_launch(void* const* d_in, const int* in_sizes, int n_in,
                              void* d_out, int out_size, void* d_ws, size_t ws_size,
                              hipStream_t stream) {
    const float* values = (const float*)d_in[0];
    const float* key_   = (const float*)d_in[1];
    const float* query  = (const float*)d_in[2];
    const int*   mask   = (const int*)d_in[3];
    const float* Wv     = (const float*)d_in[4];
    const float* Wk     = (const float*)d_in[5];
    const float* Wq     = (const float*)d_in[6];
    const float* bq     = (const float*)d_in[7];
    const float* Wo     = (const float*)d_in[8];
    const float* bo     = (const float*)d_in[9];
    float* out = (float*)d_out;

    const size_t NHLD = (size_t)NB * NH * SEQ * HD;   // 4,194,304

    unsigned short* ws = (unsigned short*)d_ws;
    unsigned short* Qp    = ws;
    unsigned short* Kp    = ws + NHLD;
    unsigned short* Vtp   = ws + 2 * NHLD;
    unsigned short* Aattn = ws + 3 * NHLD;
    unsigned short* Wob   = ws + 4 * NHLD;                  // EMB*EMB
    unsigned short* Wqb   = Wob + (size_t)EMB * EMB;
    unsigned short* Wkb   = Wqb + HD * HD;
    unsigned short* Wvb   = Wkb + HD * HD;
    unsigned short* Mb    = Wvb + HD * HD;                  // NB*SEQ bf16 mask

    cvt_kernel<<<dim3(1028), 256, 0, stream>>>(
        Wo, Wq, Wk, Wv, mask, Wob, Wqb, Wkb, Wvb, Mb);
    qkv_kernel<<<dim3(SEQ / 128, NH, 3 * NB), 256, 0, stream>>>(
        query, key_, values, Wqb, Wkb, Wvb, bq, mask, Qp, Kp, Vtp);
    flash_kernel<<<dim3(NB * NH, SEQ / 128), 256, 0, stream>>>(
        Qp, Kp, Vtp, Mb, Aattn);
    outproj_kernel<<<dim3(EMB / 128, NB * SEQ / 128), 256, 0, stream>>>(
        Aattn, Wob, bo, out);
}